// Round 7
// baseline (327.524 us; speedup 1.0000x reference)
//
#include <hip/hip_runtime.h>
#include <math.h>

// ProbAttention (Informer ProbSparse) — B=8 L=2048 H=8 D=64 u=40
// q/k/v reshape(B,H,L,D) is a flat reinterpretation -> treat as (BH=64, L, D) contiguous.
#define LSEQ 2048
#define DDIM 64
#define UU   40
#define NBH  64
#define CTX_ELEMS (NBH*UU*DDIM)   // 163840

// ---------------- K12: fused QK_sample + M, 4-lanes-per-l geometry ----------------
// 2048 blocks: bh = b&63 (XCD-local: XCD = bh%8), ltile = b>>6 (64 l per block).
// Proven 88 µs @ 73% occupancy; bound by scattered-L2 gather delivery (~15 TB/s).
__global__ __launch_bounds__(256, 4) void k12_sample_m(
    const float* __restrict__ q, const float* __restrict__ k,
    const int* __restrict__ idxs, float* __restrict__ M) {
  int b = blockIdx.x;
  int bh = b & 63;
  int ltile = b >> 6;
  int t = threadIdx.x;
  int g = t >> 2;
  int sub = t & 3;
  int l = ltile * 64 + g;

  const float4* qr = (const float4*)(q + (size_t)(bh * LSEQ + l) * DDIM);
  float4 qv[4];
#pragma unroll
  for (int m = 0; m < 4; ++m) qv[m] = qr[4 * m + sub];

  const float* kbase = k + (size_t)bh * LSEQ * DDIM;
  const int4* ir = (const int4*)(idxs + l * UU);

  float mx = -INFINITY, sm = 0.f;
#pragma unroll 1
  for (int s4 = 0; s4 < UU / 4; ++s4) {
    int4 jv = ir[s4];
    const float4* k0 = (const float4*)(kbase + (size_t)jv.x * DDIM);
    const float4* k1 = (const float4*)(kbase + (size_t)jv.y * DDIM);
    const float4* k2 = (const float4*)(kbase + (size_t)jv.z * DDIM);
    const float4* k3 = (const float4*)(kbase + (size_t)jv.w * DDIM);
    float d0 = 0.f, d1 = 0.f, d2 = 0.f, d3 = 0.f;
#pragma unroll
    for (int m = 0; m < 4; ++m) {
      float4 a = k0[4 * m + sub]; float4 x = qv[m];
      d0 += x.x * a.x + x.y * a.y + x.z * a.z + x.w * a.w;
    }
#pragma unroll
    for (int m = 0; m < 4; ++m) {
      float4 a = k1[4 * m + sub]; float4 x = qv[m];
      d1 += x.x * a.x + x.y * a.y + x.z * a.z + x.w * a.w;
    }
#pragma unroll
    for (int m = 0; m < 4; ++m) {
      float4 a = k2[4 * m + sub]; float4 x = qv[m];
      d2 += x.x * a.x + x.y * a.y + x.z * a.z + x.w * a.w;
    }
#pragma unroll
    for (int m = 0; m < 4; ++m) {
      float4 a = k3[4 * m + sub]; float4 x = qv[m];
      d3 += x.x * a.x + x.y * a.y + x.z * a.z + x.w * a.w;
    }
    d0 += __shfl_xor(d0, 1, 64); d0 += __shfl_xor(d0, 2, 64);
    d1 += __shfl_xor(d1, 1, 64); d1 += __shfl_xor(d1, 2, 64);
    d2 += __shfl_xor(d2, 1, 64); d2 += __shfl_xor(d2, 2, 64);
    d3 += __shfl_xor(d3, 1, 64); d3 += __shfl_xor(d3, 2, 64);
    mx = fmaxf(fmaxf(fmaxf(mx, d0), fmaxf(d1, d2)), d3);
    sm += (d0 + d1) + (d2 + d3);
  }
  if (sub == 0) M[bh * LSEQ + l] = mx - sm * (1.0f / (float)LSEQ);
}

// ---------------- KF: redundant-topk + scores + softmax + attn + context ----------------
// 512 blocks: bh = b&63 (XCD-local), ug = b>>6 (5 u each, u0 = ug*5).
// Each block redoes its head's full top-40 from M (deterministic, ~2 µs) — kills two
// dispatch boundaries. Then: scores (4-lane geometry) -> sct LDS -> softmax (wave/row)
// -> normalized attn store -> context from L2-streamed v -> direct ctx store.
__global__ __launch_bounds__(256, 3) void kf_fused(
    const float* __restrict__ q, const float* __restrict__ k,
    const float* __restrict__ v, const float* __restrict__ M,
    float* __restrict__ attn, float* __restrict__ ctx) {
  __shared__ float sct[5 * LSEQ];       // 40 KB, [u][l]
  __shared__ float red[4 * 5 * 64];     // 5 KB
  __shared__ float swv[4];
  __shared__ int   swi[4];
  __shared__ int   win;
  __shared__ int   topq[5];

  int b = blockIdx.x;
  int bh = b & 63;
  int ug = b >> 6;
  int u0 = ug * 5;
  int t = threadIdx.x;
  int w = t >> 6, lane = t & 63;

  // ---- Phase T: redundant top-40 (desc value, tie -> smaller index) ----
  float mv[8];
#pragma unroll
  for (int j = 0; j < 8; ++j) mv[j] = M[bh * LSEQ + t + 256 * j];
  for (int it = 0; it < UU; ++it) {
    float bv = -INFINITY; int bi = 0x7fffffff;
#pragma unroll
    for (int j = 0; j < 8; ++j) {
      if (mv[j] > bv) { bv = mv[j]; bi = t + 256 * j; }  // ascending i: first wins ties
    }
#pragma unroll
    for (int off = 32; off > 0; off >>= 1) {
      float ov = __shfl_xor(bv, off, 64);
      int   oi = __shfl_xor(bi, off, 64);
      if (ov > bv || (ov == bv && oi < bi)) { bv = ov; bi = oi; }
    }
    if (lane == 0) { swv[w] = bv; swi[w] = bi; }
    __syncthreads();
    if (t == 0) {
      float fv = swv[0]; int fi = swi[0];
#pragma unroll
      for (int j = 1; j < 4; ++j) {
        if (swv[j] > fv || (swv[j] == fv && swi[j] < fi)) { fv = swv[j]; fi = swi[j]; }
      }
      win = fi;
      if (it >= u0 && it < u0 + 5) topq[it - u0] = fi;
    }
    __syncthreads();
    int wi = win;
    if ((wi & 255) == t) mv[wi >> 8] = -INFINITY;
  }

  // ---- Phase S: scores -> sct[u][l], 4-lane geometry ----
  int g = t >> 2;
  int sub = t & 3;
  float4 qv[5][4];
#pragma unroll
  for (int u = 0; u < 5; ++u) {
    int qi = topq[u];
    const float4* qr = (const float4*)(q + (size_t)(bh * LSEQ + qi) * DDIM);
#pragma unroll
    for (int m = 0; m < 4; ++m) qv[u][m] = qr[4 * m + sub];
  }
  const float* kb = k + (size_t)bh * LSEQ * DDIM;
#pragma unroll 1
  for (int p = 0; p < 32; ++p) {
    int l = p * 64 + g;
    const float4* kr = (const float4*)(kb + (size_t)l * DDIM);
    float4 ks[4];
#pragma unroll
    for (int m = 0; m < 4; ++m) ks[m] = kr[4 * m + sub];
#pragma unroll
    for (int u = 0; u < 5; ++u) {
      float s = 0.f;
#pragma unroll
      for (int m = 0; m < 4; ++m) {
        float4 x = qv[u][m], a = ks[m];
        s += x.x * a.x + x.y * a.y + x.z * a.z + x.w * a.w;
      }
      s += __shfl_xor(s, 1, 64);
      s += __shfl_xor(s, 2, 64);
      if (sub == 0) sct[u * LSEQ + l] = s * 0.125f;
    }
  }
  __syncthreads();

  // ---- Phase X: softmax per row; wave w -> rows w, w+4 (wave 0 does row 4) ----
  for (int r = w; r < 5; r += 4) {
    float* row = sct + r * LSEQ;
    float vv[32];
    float mx = -INFINITY;
#pragma unroll
    for (int j = 0; j < 32; ++j) { vv[j] = row[lane + 64 * j]; mx = fmaxf(mx, vv[j]); }
#pragma unroll
    for (int off = 32; off > 0; off >>= 1) mx = fmaxf(mx, __shfl_xor(mx, off, 64));
    float sm = 0.f;
#pragma unroll
    for (int j = 0; j < 32; ++j) { vv[j] = __expf(vv[j] - mx); sm += vv[j]; }
#pragma unroll
    for (int off = 32; off > 0; off >>= 1) sm += __shfl_xor(sm, off, 64);
    float inv = 1.0f / sm;
    float* ap = attn + (size_t)(bh * UU + u0 + r) * LSEQ;
#pragma unroll
    for (int j = 0; j < 32; ++j) {
      float pn = vv[j] * inv;
      ap[lane + 64 * j] = pn;
      row[lane + 64 * j] = pn;
    }
  }
  __syncthreads();

  // ---- Phase C: ctx[u][d] = sum_l p[u][l] * v[l][d]; wave w owns l-strip ----
  int d = lane;
  const float* vb = v + (size_t)bh * LSEQ * DDIM;
  float acc[5] = {0.f, 0.f, 0.f, 0.f, 0.f};
  int l0 = w * 512;
#pragma unroll 1
  for (int i = 0; i < 128; ++i) {
    int l = l0 + i * 4;
    float4 p0 = *(float4*)&sct[0 * LSEQ + l];   // broadcast ds_read_b128
    float4 p1 = *(float4*)&sct[1 * LSEQ + l];
    float4 p2 = *(float4*)&sct[2 * LSEQ + l];
    float4 p3 = *(float4*)&sct[3 * LSEQ + l];
    float4 p4 = *(float4*)&sct[4 * LSEQ + l];
    float v0 = vb[(size_t)(l + 0) * DDIM + d];
    float v1 = vb[(size_t)(l + 1) * DDIM + d];
    float v2 = vb[(size_t)(l + 2) * DDIM + d];
    float v3 = vb[(size_t)(l + 3) * DDIM + d];
    acc[0] = fmaf(p0.x, v0, fmaf(p0.y, v1, fmaf(p0.z, v2, fmaf(p0.w, v3, acc[0]))));
    acc[1] = fmaf(p1.x, v0, fmaf(p1.y, v1, fmaf(p1.z, v2, fmaf(p1.w, v3, acc[1]))));
    acc[2] = fmaf(p2.x, v0, fmaf(p2.y, v1, fmaf(p2.z, v2, fmaf(p2.w, v3, acc[2]))));
    acc[3] = fmaf(p3.x, v0, fmaf(p3.y, v1, fmaf(p3.z, v2, fmaf(p3.w, v3, acc[3]))));
    acc[4] = fmaf(p4.x, v0, fmaf(p4.y, v1, fmaf(p4.z, v2, fmaf(p4.w, v3, acc[4]))));
  }
#pragma unroll
  for (int u = 0; u < 5; ++u) red[(w * 5 + u) * 64 + d] = acc[u];
  __syncthreads();
  if (w == 0) {
#pragma unroll
    for (int u = 0; u < 5; ++u) {
      float s = red[(0 * 5 + u) * 64 + d] + red[(1 * 5 + u) * 64 + d] +
                red[(2 * 5 + u) * 64 + d] + red[(3 * 5 + u) * 64 + d];
      ctx[(size_t)(bh * UU + u0 + u) * DDIM + d] = s;
    }
  }
}

extern "C" void kernel_launch(void* const* d_in, const int* in_sizes, int n_in,
                              void* d_out, int out_size, void* d_ws, size_t ws_size,
                              hipStream_t stream) {
  const float* q   = (const float*)d_in[0];
  const float* k   = (const float*)d_in[1];
  const float* v   = (const float*)d_in[2];
  const int*   idx = (const int*)d_in[3];

  float* ctx  = (float*)d_out;                  // [NBH, UU, DDIM]
  float* attn = (float*)d_out + CTX_ELEMS;      // [NBH, UU, LSEQ]

  float* M    = (float*)d_ws;                   // 131072 f

  k12_sample_m<<<NBH * 32, 256, 0, stream>>>(q, k, idx, M);
  kf_fused<<<NBH * 8, 256, 0, stream>>>(q, k, v, M, attn, ctx);
}